// Round 10
// baseline (151.517 us; speedup 1.0000x reference)
//
#include <hip/hip_runtime.h>
#include <hip/hip_bf16.h>

#define N_NODES 100000
#define N_EDGES 1600000
#define D 128

#define NBUK 1024
#define BSH 7               // bucket = dst >> 7  (128 nodes per bucket)
#define NAGG ((N_NODES + 127) >> BSH)   // 782 buckets contain nodes
#define CAP 2560            // per-bucket capacity (mean 2046, std ~45 -> 11 sigma)
#define NSCAT 256           // scatter blocks in the fused kernel
#define PA_EPB 6250         // 256 * 6250 = 1.6M edges
#define NGB ((N_NODES / 16 + 15) / 16)  // 391 gemm blocks (16 waves each)
#define SRC_MASK 0x01FFFFFF // low 25 bits: src (< 2^17); bits 25..31: dst&127

typedef __attribute__((ext_vector_type(8))) short bf16x8;  // 8 bf16 (4 VGPRs)
typedef __attribute__((ext_vector_type(4))) float f32x4;

static __device__ __forceinline__ short f2bf(float f) {
    unsigned u = __builtin_bit_cast(unsigned, f);
    u += 0x7FFFu + ((u >> 16) & 1u);                 // RNE
    return (short)(u >> 16);
}
static __device__ __forceinline__ float bf2f(unsigned short h) {
    unsigned u = ((unsigned)h) << 16;
    return __builtin_bit_cast(float, u);
}

// ---------------------------------------------------------------------------
// Wt[c][k] = bf16(W[k][c]) — 32 KB, built once; also zeroes gcur.
// ---------------------------------------------------------------------------
__global__ void wt_kernel(const float* __restrict__ w, short* __restrict__ wt,
                          int* __restrict__ gcur) {
    const int i = blockIdx.x * blockDim.x + threadIdx.x;
    if (i < D * D) {
        const int k = i / D, c = i % D;
        wt[c * D + k] = f2bf(w[i]);
    }
    if (i < NBUK) gcur[i] = 0;
}

// ---------------------------------------------------------------------------
// Fused independent work: blocks [0,NSCAT) do the bucket scatter (latency-
// bound), blocks [NSCAT, NSCAT+NGB) do the MFMA GEMM (compute-bound). The
// two halves have no data dependency and overlap on the machine.
// ---------------------------------------------------------------------------
__global__ __launch_bounds__(1024, 8) void gemm_scatter_kernel(
    const float* __restrict__ x, const short* __restrict__ wt,
    short* __restrict__ sup, const int* __restrict__ dst,
    const int* __restrict__ src, const float* __restrict__ ew,
    int* __restrict__ gcur, int2* __restrict__ inter_sw) {
    __shared__ int h[NBUK];
    const int t = threadIdx.x;

    if (blockIdx.x < NSCAT) {
        // ---- bucket scatter (fixed-capacity regions) ----
        if (t < NBUK) h[t] = 0;
        __syncthreads();
        const int beg = blockIdx.x * PA_EPB;
        const int end = min(beg + PA_EPB, N_EDGES);
        for (int i = beg + t; i < end; i += 1024)
            atomicAdd(&h[dst[i] >> BSH], 1);
        __syncthreads();
        if (t < NBUK) {
            const int c = h[t];
            h[t] = c ? (t * CAP + atomicAdd(&gcur[t], c)) : 0;
        }
        __syncthreads();
        for (int i = beg + t; i < end; i += 1024) {
            const int d = dst[i];
            const int pos = atomicAdd(&h[d >> BSH], 1);
            inter_sw[pos] = make_int2(src[i] | ((d & 127) << 25),
                                      __float_as_int(ew[i]));
        }
        return;
    }

    // ---- GEMM: support(bf16) = X @ W via MFMA, one wave per 16 rows ----
    const int wid = (blockIdx.x - NSCAT) * 16 + (t >> 6);
    if (wid >= N_NODES / 16) return;
    const int l = t & 63;
    const int r = l & 15, g = l >> 4;
    const size_t row0 = (size_t)wid * 16;

    bf16x8 a[4];
    const float* xp = x + (row0 + r) * D + g * 8;
#pragma unroll
    for (int ks = 0; ks < 4; ++ks) {
        const float4 f0 = *reinterpret_cast<const float4*>(xp + ks * 32);
        const float4 f1 = *reinterpret_cast<const float4*>(xp + ks * 32 + 4);
        bf16x8 tt;
        tt[0] = f2bf(f0.x); tt[1] = f2bf(f0.y); tt[2] = f2bf(f0.z); tt[3] = f2bf(f0.w);
        tt[4] = f2bf(f1.x); tt[5] = f2bf(f1.y); tt[6] = f2bf(f1.z); tt[7] = f2bf(f1.w);
        a[ks] = tt;
    }

#pragma unroll
    for (int nt = 0; nt < 8; ++nt) {
        f32x4 acc = {0.f, 0.f, 0.f, 0.f};
        const short* wp = wt + (size_t)(nt * 16 + r) * D + g * 8;
#pragma unroll
        for (int ks = 0; ks < 4; ++ks) {
            const bf16x8 b = *reinterpret_cast<const bf16x8*>(wp + ks * 32);
            acc = __builtin_amdgcn_mfma_f32_16x16x32_bf16(a[ks], b, acc, 0, 0, 0);
        }
        short* sp = sup + (row0 + g * 4) * D + nt * 16 + r;
#pragma unroll
        for (int q = 0; q < 4; ++q) sp[q * D] = f2bf(acc[q]);
    }
}

// ---------------------------------------------------------------------------
// Fused sort+aggregate: one 512-thread block per bucket. Phase 1: LDS
// counting-sort into a 20 KB edge buffer (payloads in 5 named registers).
// Phase 2: register aggregation, 8 waves x 16 nodes; per node 8 edge-groups
// x 8 feature-lanes (two bf16x8 loads per lane per edge) -> 8 independent
// row-gathers in flight per wave; 3-step shfl_xor combine; group 0 writes.
// ---------------------------------------------------------------------------
__global__ __launch_bounds__(512) void sortagg_kernel(
    const int* __restrict__ gcur, const int2* __restrict__ inter_sw,
    const short* __restrict__ sup, const float* __restrict__ bias,
    float* __restrict__ out) {
    __shared__ int2 eb[CAP];          // 20 KB sorted edge payloads
    __shared__ int st[128];           // node segment start (within eb)
    __shared__ int cur[128];          // scatter cursor -> segment end
    const int b = blockIdx.x, t = threadIdx.x;
    const int cnt = gcur[b];
    const int2* in = inter_sw + (size_t)b * CAP;

    if (t < 128) st[t] = 0;           // reuse st as histogram first
    __syncthreads();

    // hold up to 5 payloads in named registers (CAP/512 == 5), count in hist
    int2 e0, e1, e2, e3, e4;
    const int i0 = t, i1 = t + 512, i2 = t + 1024, i3 = t + 1536, i4 = t + 2048;
    if (i0 < cnt) { e0 = in[i0]; atomicAdd(&st[(unsigned)e0.x >> 25], 1); }
    if (i1 < cnt) { e1 = in[i1]; atomicAdd(&st[(unsigned)e1.x >> 25], 1); }
    if (i2 < cnt) { e2 = in[i2]; atomicAdd(&st[(unsigned)e2.x >> 25], 1); }
    if (i3 < cnt) { e3 = in[i3]; atomicAdd(&st[(unsigned)e3.x >> 25], 1); }
    if (i4 < cnt) { e4 = in[i4]; atomicAdd(&st[(unsigned)e4.x >> 25], 1); }
    __syncthreads();

    // exclusive scan over 128 bins (Hillis-Steele on threads 0..127)
    int hv = 0;
    if (t < 128) { hv = st[t]; cur[t] = hv; }
    __syncthreads();
    for (int o = 1; o < 128; o <<= 1) {
        int v = 0;
        if (t < 128 && t >= o) v = cur[t - o];
        __syncthreads();
        if (t < 128) cur[t] += v;
        __syncthreads();
    }
    if (t < 128) {
        const int s = cur[t] - hv;    // exclusive
        st[t] = s;
        cur[t] = s;
    }
    __syncthreads();

    // scatter payloads into sorted LDS positions (strip d7, keep src+weight)
    if (i0 < cnt) eb[atomicAdd(&cur[(unsigned)e0.x >> 25], 1)] = make_int2(e0.x & SRC_MASK, e0.y);
    if (i1 < cnt) eb[atomicAdd(&cur[(unsigned)e1.x >> 25], 1)] = make_int2(e1.x & SRC_MASK, e1.y);
    if (i2 < cnt) eb[atomicAdd(&cur[(unsigned)e2.x >> 25], 1)] = make_int2(e2.x & SRC_MASK, e2.y);
    if (i3 < cnt) eb[atomicAdd(&cur[(unsigned)e3.x >> 25], 1)] = make_int2(e3.x & SRC_MASK, e3.y);
    if (i4 < cnt) eb[atomicAdd(&cur[(unsigned)e4.x >> 25], 1)] = make_int2(e4.x & SRC_MASK, e4.y);
    __syncthreads();

    // phase 2: aggregate. wave wv handles local nodes wv*16 .. wv*16+15.
    const int wv = t >> 6, lane = t & 63;
    const int g = lane >> 3;          // edge group 0..7
    const int fl = lane & 7;          // feature lane: features fl*16..fl*16+15

    const float4 b0 = *reinterpret_cast<const float4*>(&bias[fl * 16]);
    const float4 b1 = *reinterpret_cast<const float4*>(&bias[fl * 16 + 4]);
    const float4 b2 = *reinterpret_cast<const float4*>(&bias[fl * 16 + 8]);
    const float4 b3 = *reinterpret_cast<const float4*>(&bias[fl * 16 + 12]);

    for (int k = 0; k < 16; ++k) {
        const int nl = wv * 16 + k;
        const int node = (b << BSH) + nl;
        if (node >= N_NODES) break;
        const int end = cur[nl];      // cur == segment end now

        float acc[16];
#pragma unroll
        for (int q = 0; q < 16; ++q) acc[q] = 0.f;

        for (int i = st[nl] + g; i < end; i += 8) {
            const int2 sw = eb[i];
            const float w = __int_as_float(sw.y);
            const short* rp = &sup[(size_t)sw.x * D + fl * 16];
            const bf16x8 v0 = *reinterpret_cast<const bf16x8*>(rp);
            const bf16x8 v1 = *reinterpret_cast<const bf16x8*>(rp + 8);
#pragma unroll
            for (int q = 0; q < 8; ++q) {
                acc[q] = fmaf(w, bf2f((unsigned short)v0[q]), acc[q]);
                acc[8 + q] = fmaf(w, bf2f((unsigned short)v1[q]), acc[8 + q]);
            }
        }
#pragma unroll
        for (int q = 0; q < 16; ++q) {
            acc[q] += __shfl_xor(acc[q], 8);
            acc[q] += __shfl_xor(acc[q], 16);
            acc[q] += __shfl_xor(acc[q], 32);
        }
        if (g == 0) {
            float* o = &out[(size_t)node * D + fl * 16];
            reinterpret_cast<float4*>(o)[0] =
                make_float4(acc[0] + b0.x, acc[1] + b0.y, acc[2] + b0.z, acc[3] + b0.w);
            reinterpret_cast<float4*>(o)[1] =
                make_float4(acc[4] + b1.x, acc[5] + b1.y, acc[6] + b1.z, acc[7] + b1.w);
            reinterpret_cast<float4*>(o)[2] =
                make_float4(acc[8] + b2.x, acc[9] + b2.y, acc[10] + b2.z, acc[11] + b2.w);
            reinterpret_cast<float4*>(o)[3] =
                make_float4(acc[12] + b3.x, acc[13] + b3.y, acc[14] + b3.z, acc[15] + b3.w);
        }
    }
}

extern "C" void kernel_launch(void* const* d_in, const int* in_sizes, int n_in,
                              void* d_out, int out_size, void* d_ws, size_t ws_size,
                              hipStream_t stream) {
    const float* x      = (const float*)d_in[0];   // [N_NODES, D]
    const float* weight = (const float*)d_in[1];   // [D, D]
    const float* bias   = (const float*)d_in[2];   // [D]
    const int*   eidx   = (const int*)d_in[3];     // [2, N_EDGES] int32
    const float* ew     = (const float*)d_in[4];   // [N_EDGES]
    float* out = (float*)d_out;

    const int* dst_idx = eidx;                     // edge_index[0] (receiver)
    const int* src_idx = eidx + N_EDGES;           // edge_index[1] (neighbor)

    // workspace layout (16B-aligned chunks), total ~46.7 MB
    char* p = (char*)d_ws;
    short* sup       = (short*)p;  p += (size_t)N_NODES * D * 2;   // 25,600,000
    short* wt        = (short*)p;  p += (size_t)D * D * 2;         // 32,768
    int*   gcur      = (int*)p;    p += NBUK * 4;                  // 4,096
    int2*  inter_sw  = (int2*)p;   p += (size_t)NBUK * CAP * 8;    // 20,971,520

    // 1) Wt = bf16(W^T) + zero gcur
    wt_kernel<<<(D * D + 255) / 256, 256, 0, stream>>>(weight, wt, gcur);

    // 2) fused: bucket scatter (blocks 0..255) || MFMA GEMM (blocks 256..646)
    gemm_scatter_kernel<<<NSCAT + NGB, 1024, 0, stream>>>(
        x, wt, sup, dst_idx, src_idx, ew, gcur, inter_sw);

    // 3) fused per-bucket LDS counting-sort + register aggregation
    sortagg_kernel<<<NAGG, 512, 0, stream>>>(gcur, inter_sw, sup, bias, out);
}

// Round 11
// 133.137 us; speedup vs baseline: 1.1381x; 1.1381x over previous
//
#include <hip/hip_runtime.h>
#include <hip/hip_bf16.h>

#define N_NODES 100000
#define N_EDGES 1600000
#define D 128

#define BSH 6               // bucket = dst >> 6  (64 nodes per bucket)
#define NBUK 1563           // ceil(100000 / 64)
#define CAP 1344            // per-bucket capacity (mean 1024, std ~32 -> 10 sigma)
#define NSCAT 256           // scatter blocks in the fused kernel
#define PA_EPB 6250         // 256 * 6250 = 1.6M edges
#define NGB ((N_NODES / 16 + 15) / 16)  // 391 gemm blocks (16 waves each)
#define SRC_MASK 0x03FFFFFF // low 26 bits: src (< 2^17); bits 26..31: dst&63

typedef __attribute__((ext_vector_type(8))) short bf16x8;  // 8 bf16 (4 VGPRs)
typedef __attribute__((ext_vector_type(4))) float f32x4;

static __device__ __forceinline__ short f2bf(float f) {
    unsigned u = __builtin_bit_cast(unsigned, f);
    u += 0x7FFFu + ((u >> 16) & 1u);                 // RNE
    return (short)(u >> 16);
}
static __device__ __forceinline__ float bf2f(unsigned short h) {
    unsigned u = ((unsigned)h) << 16;
    return __builtin_bit_cast(float, u);
}

// ---------------------------------------------------------------------------
// Wt[c][k] = bf16(W[k][c]) — 32 KB, built once; also zeroes gcur.
// ---------------------------------------------------------------------------
__global__ void wt_kernel(const float* __restrict__ w, short* __restrict__ wt,
                          int* __restrict__ gcur) {
    const int i = blockIdx.x * blockDim.x + threadIdx.x;
    if (i < D * D) {
        const int k = i / D, c = i % D;
        wt[c * D + k] = f2bf(w[i]);
    }
    if (i < NBUK) gcur[i] = 0;
}

// ---------------------------------------------------------------------------
// Fused independent work: blocks [0,NSCAT) do the bucket scatter (latency-
// bound), blocks [NSCAT, NSCAT+NGB) do the MFMA GEMM (compute-bound).
// ---------------------------------------------------------------------------
__global__ __launch_bounds__(1024, 8) void gemm_scatter_kernel(
    const float* __restrict__ x, const short* __restrict__ wt,
    short* __restrict__ sup, const int* __restrict__ dst,
    const int* __restrict__ src, const float* __restrict__ ew,
    int* __restrict__ gcur, int2* __restrict__ inter_sw) {
    __shared__ int h[NBUK];
    const int t = threadIdx.x;

    if (blockIdx.x < NSCAT) {
        // ---- bucket scatter (fixed-capacity regions) ----
        for (int j = t; j < NBUK; j += 1024) h[j] = 0;
        __syncthreads();
        const int beg = blockIdx.x * PA_EPB;
        const int end = min(beg + PA_EPB, N_EDGES);
        for (int i = beg + t; i < end; i += 1024)
            atomicAdd(&h[dst[i] >> BSH], 1);
        __syncthreads();
        for (int j = t; j < NBUK; j += 1024) {
            const int c = h[j];
            h[j] = c ? (j * CAP + atomicAdd(&gcur[j], c)) : 0;
        }
        __syncthreads();
        for (int i = beg + t; i < end; i += 1024) {
            const int d = dst[i];
            const int pos = atomicAdd(&h[d >> BSH], 1);
            inter_sw[pos] = make_int2(src[i] | ((d & 63) << 26),
                                      __float_as_int(ew[i]));
        }
        return;
    }

    // ---- GEMM: support(bf16) = X @ W via MFMA, one wave per 16 rows ----
    const int wid = (blockIdx.x - NSCAT) * 16 + (t >> 6);
    if (wid >= N_NODES / 16) return;
    const int l = t & 63;
    const int r = l & 15, g = l >> 4;
    const size_t row0 = (size_t)wid * 16;

    bf16x8 a[4];
    const float* xp = x + (row0 + r) * D + g * 8;
#pragma unroll
    for (int ks = 0; ks < 4; ++ks) {
        const float4 f0 = *reinterpret_cast<const float4*>(xp + ks * 32);
        const float4 f1 = *reinterpret_cast<const float4*>(xp + ks * 32 + 4);
        bf16x8 tt;
        tt[0] = f2bf(f0.x); tt[1] = f2bf(f0.y); tt[2] = f2bf(f0.z); tt[3] = f2bf(f0.w);
        tt[4] = f2bf(f1.x); tt[5] = f2bf(f1.y); tt[6] = f2bf(f1.z); tt[7] = f2bf(f1.w);
        a[ks] = tt;
    }

#pragma unroll
    for (int nt = 0; nt < 8; ++nt) {
        f32x4 acc = {0.f, 0.f, 0.f, 0.f};
        const short* wp = wt + (size_t)(nt * 16 + r) * D + g * 8;
#pragma unroll
        for (int ks = 0; ks < 4; ++ks) {
            const bf16x8 b = *reinterpret_cast<const bf16x8*>(wp + ks * 32);
            acc = __builtin_amdgcn_mfma_f32_16x16x32_bf16(a[ks], b, acc, 0, 0, 0);
        }
        short* sp = sup + (row0 + g * 4) * D + nt * 16 + r;
#pragma unroll
        for (int q = 0; q < 4; ++q) sp[q * D] = f2bf(acc[q]);
    }
}

// ---------------------------------------------------------------------------
// Fused sort+aggregate: one 512-thread block per 64-node bucket (1563 blocks
// -> ~6 queued/CU, 4 co-resident at ~10.8 KB LDS; 24 VGPR). Phase 1: LDS
// counting-sort (3 payload regs, 64-bin single-wave shuffle scan). Phase 2:
// proven R7 structure — 8 waves x 8 nodes, 4 edge-groups x 16 feature-lanes,
// simple compiler-pipelined gather loop, shfl_xor combine, group 0 writes.
// ---------------------------------------------------------------------------
__global__ __launch_bounds__(512) void sortagg_kernel(
    const int* __restrict__ gcur, const int2* __restrict__ inter_sw,
    const short* __restrict__ sup, const float* __restrict__ bias,
    float* __restrict__ out) {
    __shared__ int2 eb[CAP];          // 10.5 KB sorted edge payloads
    __shared__ int st[64];            // node segment start (within eb)
    __shared__ int cur[64];           // scatter cursor -> segment end
    const int b = blockIdx.x, t = threadIdx.x;
    const int cnt = gcur[b];
    const int2* in = inter_sw + (size_t)b * CAP;

    if (t < 64) st[t] = 0;            // st doubles as histogram first
    __syncthreads();

    // hold up to 3 payloads in named registers (CAP <= 3*512), count in hist
    int2 e0, e1, e2;
    const int i0 = t, i1 = t + 512, i2 = t + 1024;
    if (i0 < cnt) { e0 = in[i0]; atomicAdd(&st[(unsigned)e0.x >> 26], 1); }
    if (i1 < cnt) { e1 = in[i1]; atomicAdd(&st[(unsigned)e1.x >> 26], 1); }
    if (i2 < cnt) { e2 = in[i2]; atomicAdd(&st[(unsigned)e2.x >> 26], 1); }
    __syncthreads();

    // exclusive scan over 64 bins — single wave, shuffle scan
    if (t < 64) {
        const int hv = st[t];
        int s = hv;
#pragma unroll
        for (int o = 1; o < 64; o <<= 1) {
            const int v = __shfl_up(s, o);
            if (t >= o) s += v;
        }
        st[t] = s - hv;               // exclusive
        cur[t] = s - hv;
    }
    __syncthreads();

    // scatter payloads into sorted LDS positions (strip d6, keep src+weight)
    if (i0 < cnt) eb[atomicAdd(&cur[(unsigned)e0.x >> 26], 1)] = make_int2(e0.x & SRC_MASK, e0.y);
    if (i1 < cnt) eb[atomicAdd(&cur[(unsigned)e1.x >> 26], 1)] = make_int2(e1.x & SRC_MASK, e1.y);
    if (i2 < cnt) eb[atomicAdd(&cur[(unsigned)e2.x >> 26], 1)] = make_int2(e2.x & SRC_MASK, e2.y);
    __syncthreads();

    // phase 2: aggregate. wave wv handles local nodes wv*8 .. wv*8+7.
    const int wv = t >> 6, lane = t & 63;
    const int g = lane >> 4;          // edge group 0..3
    const int fl = lane & 15;         // feature lane: features fl*8..fl*8+7

    const float4 b0 = *reinterpret_cast<const float4*>(&bias[fl * 8]);
    const float4 b1 = *reinterpret_cast<const float4*>(&bias[fl * 8 + 4]);

    for (int k = 0; k < 8; ++k) {
        const int nl = wv * 8 + k;
        const int node = (b << BSH) + nl;
        if (node >= N_NODES) break;
        const int beg = st[nl], end = cur[nl];   // cur == segment end now

        float acc[8] = {0, 0, 0, 0, 0, 0, 0, 0};
        for (int i = beg + g; i < end; i += 4) {
            const int2 sw = eb[i];
            const float w = __int_as_float(sw.y);
            const bf16x8 v = *reinterpret_cast<const bf16x8*>(
                &sup[(size_t)sw.x * D + fl * 8]);
#pragma unroll
            for (int q = 0; q < 8; ++q)
                acc[q] = fmaf(w, bf2f((unsigned short)v[q]), acc[q]);
        }
#pragma unroll
        for (int q = 0; q < 8; ++q) {
            acc[q] += __shfl_xor(acc[q], 16);
            acc[q] += __shfl_xor(acc[q], 32);
        }
        if (g == 0) {
            float* o = &out[(size_t)node * D + fl * 8];
            reinterpret_cast<float4*>(o)[0] =
                make_float4(acc[0] + b0.x, acc[1] + b0.y, acc[2] + b0.z, acc[3] + b0.w);
            reinterpret_cast<float4*>(o)[1] =
                make_float4(acc[4] + b1.x, acc[5] + b1.y, acc[6] + b1.z, acc[7] + b1.w);
        }
    }
}

extern "C" void kernel_launch(void* const* d_in, const int* in_sizes, int n_in,
                              void* d_out, int out_size, void* d_ws, size_t ws_size,
                              hipStream_t stream) {
    const float* x      = (const float*)d_in[0];   // [N_NODES, D]
    const float* weight = (const float*)d_in[1];   // [D, D]
    const float* bias   = (const float*)d_in[2];   // [D]
    const int*   eidx   = (const int*)d_in[3];     // [2, N_EDGES] int32
    const float* ew     = (const float*)d_in[4];   // [N_EDGES]
    float* out = (float*)d_out;

    const int* dst_idx = eidx;                     // edge_index[0] (receiver)
    const int* src_idx = eidx + N_EDGES;           // edge_index[1] (neighbor)

    // workspace layout (16B-aligned chunks), total ~42.5 MB
    char* p = (char*)d_ws;
    short* sup       = (short*)p;  p += (size_t)N_NODES * D * 2;   // 25,600,000
    short* wt        = (short*)p;  p += (size_t)D * D * 2;         // 32,768
    int*   gcur      = (int*)p;    p += ((NBUK * 4 + 15) / 16) * 16;  // 6,256
    int2*  inter_sw  = (int2*)p;   p += (size_t)NBUK * CAP * 8;    // 16,805,376

    // 1) Wt = bf16(W^T) + zero gcur
    wt_kernel<<<(D * D + 255) / 256, 256, 0, stream>>>(weight, wt, gcur);

    // 2) fused: bucket scatter (blocks 0..255) || MFMA GEMM (blocks 256..646)
    gemm_scatter_kernel<<<NSCAT + NGB, 1024, 0, stream>>>(
        x, wt, sup, dst_idx, src_idx, ew, gcur, inter_sw);

    // 3) fused per-bucket LDS counting-sort + register aggregation
    sortagg_kernel<<<NBUK, 512, 0, stream>>>(gcur, inter_sw, sup, bias, out);
}

// Round 12
// 130.558 us; speedup vs baseline: 1.1605x; 1.0198x over previous
//
#include <hip/hip_runtime.h>
#include <hip/hip_bf16.h>

#define N_NODES 100000
#define N_EDGES 1600000
#define D 128

#define NBUK 1024           // coarse buckets for the scatter (128 nodes each)
#define BSH 7
#define CAP 2560            // coarse region capacity (mean 2046, 11 sigma)
#define CAP_H 1344          // half-bucket eb capacity (mean 1024, 10 sigma)
#define NAGG2 (((N_NODES + 127) >> BSH) * 2)   // 1564 half-bucket blocks
#define NSCAT 256
#define PA_EPB 6250         // 256 * 6250 = 1.6M edges
#define NGB ((N_NODES / 16 + 15) / 16)  // 391 gemm blocks (16 waves each)
#define SRC_MASK 0x01FFFFFF // low 25 bits: src (< 2^17); bits 25..31: dst&127

typedef __attribute__((ext_vector_type(8))) short bf16x8;  // 8 bf16 (4 VGPRs)
typedef __attribute__((ext_vector_type(4))) float f32x4;

static __device__ __forceinline__ short f2bf(float f) {
    unsigned u = __builtin_bit_cast(unsigned, f);
    u += 0x7FFFu + ((u >> 16) & 1u);                 // RNE
    return (short)(u >> 16);
}
static __device__ __forceinline__ float bf2f(unsigned short h) {
    unsigned u = ((unsigned)h) << 16;
    return __builtin_bit_cast(float, u);
}

// ---------------------------------------------------------------------------
// Wt[c][k] = bf16(W[k][c]) — 32 KB, built once; also zeroes gcur.
// ---------------------------------------------------------------------------
__global__ void wt_kernel(const float* __restrict__ w, short* __restrict__ wt,
                          int* __restrict__ gcur) {
    const int i = blockIdx.x * blockDim.x + threadIdx.x;
    if (i < D * D) {
        const int k = i / D, c = i % D;
        wt[c * D + k] = f2bf(w[i]);
    }
    if (i < NBUK) gcur[i] = 0;
}

// ---------------------------------------------------------------------------
// Fused independent work: blocks [0,NSCAT) do the bucket scatter (latency-
// bound), blocks [NSCAT, NSCAT+NGB) do the MFMA GEMM (compute-bound).
// Scatter half: proven R8/R10 configuration (1024 coarse buckets).
// ---------------------------------------------------------------------------
__global__ __launch_bounds__(1024, 8) void gemm_scatter_kernel(
    const float* __restrict__ x, const short* __restrict__ wt,
    short* __restrict__ sup, const int* __restrict__ dst,
    const int* __restrict__ src, const float* __restrict__ ew,
    int* __restrict__ gcur, int2* __restrict__ inter_sw) {
    __shared__ int h[NBUK];
    const int t = threadIdx.x;

    if (blockIdx.x < NSCAT) {
        if (t < NBUK) h[t] = 0;
        __syncthreads();
        const int beg = blockIdx.x * PA_EPB;
        const int end = min(beg + PA_EPB, N_EDGES);
        for (int i = beg + t; i < end; i += 1024)
            atomicAdd(&h[dst[i] >> BSH], 1);
        __syncthreads();
        if (t < NBUK) {
            const int c = h[t];
            h[t] = c ? (t * CAP + atomicAdd(&gcur[t], c)) : 0;
        }
        __syncthreads();
        for (int i = beg + t; i < end; i += 1024) {
            const int d = dst[i];
            const int pos = atomicAdd(&h[d >> BSH], 1);
            inter_sw[pos] = make_int2(src[i] | ((d & 127) << 25),
                                      __float_as_int(ew[i]));
        }
        return;
    }

    // ---- GEMM: support(bf16) = X @ W via MFMA, one wave per 16 rows ----
    const int wid = (blockIdx.x - NSCAT) * 16 + (t >> 6);
    if (wid >= N_NODES / 16) return;
    const int l = t & 63;
    const int r = l & 15, g = l >> 4;
    const size_t row0 = (size_t)wid * 16;

    bf16x8 a[4];
    const float* xp = x + (row0 + r) * D + g * 8;
#pragma unroll
    for (int ks = 0; ks < 4; ++ks) {
        const float4 f0 = *reinterpret_cast<const float4*>(xp + ks * 32);
        const float4 f1 = *reinterpret_cast<const float4*>(xp + ks * 32 + 4);
        bf16x8 tt;
        tt[0] = f2bf(f0.x); tt[1] = f2bf(f0.y); tt[2] = f2bf(f0.z); tt[3] = f2bf(f0.w);
        tt[4] = f2bf(f1.x); tt[5] = f2bf(f1.y); tt[6] = f2bf(f1.z); tt[7] = f2bf(f1.w);
        a[ks] = tt;
    }

#pragma unroll
    for (int nt = 0; nt < 8; ++nt) {
        f32x4 acc = {0.f, 0.f, 0.f, 0.f};
        const short* wp = wt + (size_t)(nt * 16 + r) * D + g * 8;
#pragma unroll
        for (int ks = 0; ks < 4; ++ks) {
            const bf16x8 b = *reinterpret_cast<const bf16x8*>(wp + ks * 32);
            acc = __builtin_amdgcn_mfma_f32_16x16x32_bf16(a[ks], b, acc, 0, 0, 0);
        }
        short* sp = sup + (row0 + g * 4) * D + nt * 16 + r;
#pragma unroll
        for (int q = 0; q < 4; ++q) sp[q * D] = f2bf(acc[q]);
    }
}

// ---------------------------------------------------------------------------
// Fused sort+aggregate on HALF-buckets: 2 blocks per coarse bucket, each
// 512 threads, ~11 KB LDS -> 4 blocks/CU co-resident, 1564 blocks queued.
// Phase 1: read the coarse region (5 payload regs), filter to own 64-node
// half, LDS counting-sort (64-bin single-wave shuffle scan). Phase 2:
// proven structure — 8 waves x 8 nodes, 4 edge-groups x 16 feature-lanes,
// simple compiler-pipelined gather loop, shfl_xor combine, group 0 writes.
// ---------------------------------------------------------------------------
__global__ __launch_bounds__(512) void sortagg_kernel(
    const int* __restrict__ gcur, const int2* __restrict__ inter_sw,
    const short* __restrict__ sup, const float* __restrict__ bias,
    float* __restrict__ out) {
    __shared__ int2 eb[CAP_H];        // 10.75 KB sorted edge payloads
    __shared__ int st[64];            // node segment start (within eb)
    __shared__ int cur[64];           // scatter cursor -> segment end
    const int b = blockIdx.x, t = threadIdx.x;
    const int cb = b >> 1, hf = b & 1;
    const int cnt = gcur[cb];
    const int2* in = inter_sw + (size_t)cb * CAP;

    if (t < 64) st[t] = 0;            // st doubles as histogram first
    __syncthreads();

    // read up to 5 payloads (CAP/512), keep only own half, count in hist
    int2 e0, e1, e2, e3, e4;
    bool k0 = false, k1 = false, k2 = false, k3 = false, k4 = false;
    const int i0 = t, i1 = t + 512, i2 = t + 1024, i3 = t + 1536, i4 = t + 2048;
    if (i0 < cnt) { e0 = in[i0]; const int d7 = (unsigned)e0.x >> 25; if ((d7 >> 6) == hf) { k0 = true; atomicAdd(&st[d7 & 63], 1); } }
    if (i1 < cnt) { e1 = in[i1]; const int d7 = (unsigned)e1.x >> 25; if ((d7 >> 6) == hf) { k1 = true; atomicAdd(&st[d7 & 63], 1); } }
    if (i2 < cnt) { e2 = in[i2]; const int d7 = (unsigned)e2.x >> 25; if ((d7 >> 6) == hf) { k2 = true; atomicAdd(&st[d7 & 63], 1); } }
    if (i3 < cnt) { e3 = in[i3]; const int d7 = (unsigned)e3.x >> 25; if ((d7 >> 6) == hf) { k3 = true; atomicAdd(&st[d7 & 63], 1); } }
    if (i4 < cnt) { e4 = in[i4]; const int d7 = (unsigned)e4.x >> 25; if ((d7 >> 6) == hf) { k4 = true; atomicAdd(&st[d7 & 63], 1); } }
    __syncthreads();

    // exclusive scan over 64 bins — single wave, shuffle scan
    if (t < 64) {
        const int hv = st[t];
        int s = hv;
#pragma unroll
        for (int o = 1; o < 64; o <<= 1) {
            const int v = __shfl_up(s, o);
            if (t >= o) s += v;
        }
        st[t] = s - hv;               // exclusive
        cur[t] = s - hv;
    }
    __syncthreads();

    // scatter kept payloads into sorted LDS positions
    if (k0) eb[atomicAdd(&cur[((unsigned)e0.x >> 25) & 63], 1)] = make_int2(e0.x & SRC_MASK, e0.y);
    if (k1) eb[atomicAdd(&cur[((unsigned)e1.x >> 25) & 63], 1)] = make_int2(e1.x & SRC_MASK, e1.y);
    if (k2) eb[atomicAdd(&cur[((unsigned)e2.x >> 25) & 63], 1)] = make_int2(e2.x & SRC_MASK, e2.y);
    if (k3) eb[atomicAdd(&cur[((unsigned)e3.x >> 25) & 63], 1)] = make_int2(e3.x & SRC_MASK, e3.y);
    if (k4) eb[atomicAdd(&cur[((unsigned)e4.x >> 25) & 63], 1)] = make_int2(e4.x & SRC_MASK, e4.y);
    __syncthreads();

    // phase 2: aggregate. wave wv handles local nodes wv*8 .. wv*8+7.
    const int wv = t >> 6, lane = t & 63;
    const int g = lane >> 4;          // edge group 0..3
    const int fl = lane & 15;         // feature lane: features fl*8..fl*8+7
    const int node0 = (cb << BSH) + (hf << 6);

    const float4 b0 = *reinterpret_cast<const float4*>(&bias[fl * 8]);
    const float4 b1 = *reinterpret_cast<const float4*>(&bias[fl * 8 + 4]);

    for (int k = 0; k < 8; ++k) {
        const int nl = wv * 8 + k;
        const int node = node0 + nl;
        if (node >= N_NODES) break;
        const int beg = st[nl], end = cur[nl];   // cur == segment end now

        float acc[8] = {0, 0, 0, 0, 0, 0, 0, 0};
        for (int i = beg + g; i < end; i += 4) {
            const int2 sw = eb[i];
            const float w = __int_as_float(sw.y);
            const bf16x8 v = *reinterpret_cast<const bf16x8*>(
                &sup[(size_t)sw.x * D + fl * 8]);
#pragma unroll
            for (int q = 0; q < 8; ++q)
                acc[q] = fmaf(w, bf2f((unsigned short)v[q]), acc[q]);
        }
#pragma unroll
        for (int q = 0; q < 8; ++q) {
            acc[q] += __shfl_xor(acc[q], 16);
            acc[q] += __shfl_xor(acc[q], 32);
        }
        if (g == 0) {
            float* o = &out[(size_t)node * D + fl * 8];
            reinterpret_cast<float4*>(o)[0] =
                make_float4(acc[0] + b0.x, acc[1] + b0.y, acc[2] + b0.z, acc[3] + b0.w);
            reinterpret_cast<float4*>(o)[1] =
                make_float4(acc[4] + b1.x, acc[5] + b1.y, acc[6] + b1.z, acc[7] + b1.w);
        }
    }
}

extern "C" void kernel_launch(void* const* d_in, const int* in_sizes, int n_in,
                              void* d_out, int out_size, void* d_ws, size_t ws_size,
                              hipStream_t stream) {
    const float* x      = (const float*)d_in[0];   // [N_NODES, D]
    const float* weight = (const float*)d_in[1];   // [D, D]
    const float* bias   = (const float*)d_in[2];   // [D]
    const int*   eidx   = (const int*)d_in[3];     // [2, N_EDGES] int32
    const float* ew     = (const float*)d_in[4];   // [N_EDGES]
    float* out = (float*)d_out;

    const int* dst_idx = eidx;                     // edge_index[0] (receiver)
    const int* src_idx = eidx + N_EDGES;           // edge_index[1] (neighbor)

    // workspace layout (16B-aligned chunks), total ~46.7 MB
    char* p = (char*)d_ws;
    short* sup       = (short*)p;  p += (size_t)N_NODES * D * 2;   // 25,600,000
    short* wt        = (short*)p;  p += (size_t)D * D * 2;         // 32,768
    int*   gcur      = (int*)p;    p += NBUK * 4;                  // 4,096
    int2*  inter_sw  = (int2*)p;   p += (size_t)NBUK * CAP * 8;    // 20,971,520

    // 1) Wt = bf16(W^T) + zero gcur
    wt_kernel<<<(D * D + 255) / 256, 256, 0, stream>>>(weight, wt, gcur);

    // 2) fused: bucket scatter (blocks 0..255) || MFMA GEMM (blocks 256..646)
    gemm_scatter_kernel<<<NSCAT + NGB, 1024, 0, stream>>>(
        x, wt, sup, dst_idx, src_idx, ew, gcur, inter_sw);

    // 3) fused half-bucket LDS counting-sort + register aggregation
    sortagg_kernel<<<NAGG2, 512, 0, stream>>>(gcur, inter_sw, sup, bias, out);
}